// Round 7
// baseline (389.892 us; speedup 1.0000x reference)
//
#include <hip/hip_runtime.h>

// 6-point periodic stencil + DGPE ODE RHS on a 192^3 lattice.
// v6 (resubmit — prior run was an infra failure, not a kernel verdict).
// LDS plane-march. v1-v5 post-mortem: all variants (scalar TLP, float4
//     ILP, reg-clamp, XCD swizzle) pin at ~650 MB lane-delivered / 93-105 us
//     ~= 6.5 TB/s delivered, while HBM sits at 22-30% -> delivery-path
//     (L1 line-fill) ceiling, not HBM/MLP/occupancy. Only fix: fewer fills
//     per element. Each block owns a 4(y) x 64(z) pencil, marches 12 planes
//     along x. Per step: one 6x66 halo tile per field -> LDS (double-
//     buffered); xm/xp via per-thread register rotation (each plane read
//     once, used 3x); ym/yp/zm/zp from LDS. Field fills ~40 -> ~17 B/elem.
//     All LDS patterns stride-1 (2-way aliasing = free on 32 banks).
// Neighbor index arrays unused (arithmetic indices).

#define L     192
#define LSQ   (L * L)             // 36864
#define NTOT  (L * L * L)         // 7077888
#define YT    4                   // y rows per block tile
#define ZT    64                  // z extent per block tile
#define STEPS 12                  // planes computed per block
#define XCH   (L / STEPS)         // 16 x-chunks
#define YTL   (L / YT)            // 48
#define ZTL   (L / ZT)            // 3
#define NBLK  (YTL * ZTL * XCH)   // 2304 blocks = 9 per CU exactly
#define ROWS  (YT + 2)            // 6 (halo rows)
#define ZW    (ZT + 2)            // 66 (halo z)
#define ZPAD  68
#define PLANE_FLOATS (2 * ROWS * ZW)  // 792 per plane (both fields)

__global__ __launch_bounds__(256) void dgpe_kernel(
    const float* __restrict__ y,
    const float* __restrict__ Jarr,
    const float* __restrict__ aniso,
    const float* __restrict__ gam,
    const float* __restrict__ hdx,
    const float* __restrict__ hdy,
    const float* __restrict__ beta,
    const float* __restrict__ edis,
    float* __restrict__ out)
{
    __shared__ float lds[2][2][ROWS][ZPAD];   // [buf][field][row][z] 6528 B

    const int tid = threadIdx.x;
    const int bid = blockIdx.x;
    const int zt  = bid % ZTL;
    const int yt  = (bid / ZTL) % YTL;
    const int xc  = bid / (ZTL * YTL);
    const int y0  = yt * YT;
    const int z0  = zt * ZT;
    const int x0  = xc * STEPS;

    const int ty = tid >> 6;                  // 0..3
    const int tz = tid & 63;                  // 0..63

    // ---- loader decode: constant per thread across all steps ----
    // plane tile = 2 fields x 6 rows x 66 z = 792 floats, 4 rounds of 256
    int  lofs[4];                             // f*NTOT + yg*L + zg
    int  llf[4], llr[4], llz[4];              // lds coords
    bool lact[4];
#pragma unroll
    for (int k = 0; k < 4; ++k) {
        const int idx = k * 256 + tid;
        lact[k] = (idx < PLANE_FLOATS);
        const int cidx = lact[k] ? idx : 0;
        const int f    = cidx / (ROWS * ZW);
        const int rem  = cidx - f * (ROWS * ZW);
        const int r    = rem / ZW;
        const int zz   = rem - r * ZW;
        int yg = y0 + r - 1;  yg += (yg < 0) ? L : 0;  yg -= (yg >= L) ? L : 0;
        int zg = z0 + zz - 1; zg += (zg < 0) ? L : 0;  zg -= (zg >= L) ? L : 0;
        llf[k] = f; llr[k] = r; llz[k] = zz;
        lofs[k] = f * NTOT + yg * L + zg;
    }

#define LOADPLANE(XG, BN) do {                                          \
        const int _xo = (XG) * LSQ;                                     \
        _Pragma("unroll")                                               \
        for (int k = 0; k < 4; ++k)                                     \
            if (lact[k])                                                \
                lds[BN][llf[k]][llr[k]][llz[k]] = y[_xo + lofs[k]];     \
    } while (0)

    const int r  = ty + 1;                    // own row in tile
    const int zz = tz + 1;                    // own z in tile

    // ---- prologue: planes x0-1 -> lds[0], x0 -> lds[1] ----
    float cPX, cPP, cCX, cCP;                 // xm / center own values (x,p)
    {
        int xg = x0 - 1; xg += (xg < 0) ? L : 0;
        LOADPLANE(xg, 0);
        __syncthreads();
        cPX = lds[0][0][r][zz];
        cPP = lds[0][1][r][zz];
        LOADPLANE(x0, 1);
        __syncthreads();
        cCX = lds[1][0][r][zz];
        cCP = lds[1][1][r][zz];
    }

#define BODY(S, BC, BN) do {                                              \
        int xg = x0 + (S) + 1; xg -= (xg >= L) ? L : 0;                   \
        __syncthreads();            /* prior readers of lds[BN] done */   \
        LOADPLANE(xg, BN);                                                \
        __syncthreads();            /* writes visible */                  \
        const float cNX = lds[BN][0][r][zz];                              \
        const float cNP = lds[BN][1][r][zz];                              \
        const int   i   = (x0 + (S)) * LSQ + (y0 + ty) * L + (z0 + tz);   \
        const float Ji = Jarr[i], an = aniso[i];                          \
        const float g  = gam[i],  ed = edis[i], bt = beta[i];             \
        const float hx = hdx[i],  hy = hdy[i];                            \
        const float xym = lds[BC][0][r-1][zz], xyp = lds[BC][0][r+1][zz]; \
        const float xzm = lds[BC][0][r][zz-1], xzp = lds[BC][0][r][zz+1]; \
        const float pym = lds[BC][1][r-1][zz], pyp = lds[BC][1][r+1][zz]; \
        const float pzm = lds[BC][1][r][zz-1], pzp = lds[BC][1][r][zz+1]; \
        const float xL = Ji * (cPX + cNX + xym + xyp + an * (xzm + xzp)); \
        const float yL = Ji * (cPP + cNP + pym + pyp + an * (pzm + pzp)); \
        const float r2    = cCX * cCX + cCP * cCP;                        \
        const float cross = xL * cCP - yL * cCX;                          \
        out[i]        =  g * cCP * cross + ed * cCP - yL + hy + bt * r2 * cCP; \
        out[i + NTOT] = -g * cCX * cross - ed * cCX + xL - hx - bt * r2 * cCX; \
        cPX = cCX; cPP = cCP; cCX = cNX; cCP = cNP;                       \
    } while (0)

    // ---- main march: 12 planes, buffers alternate via 2-step unroll ----
    for (int s2 = 0; s2 < STEPS; s2 += 2) {
        BODY(s2,     1, 0);
        BODY(s2 + 1, 0, 1);
    }
}

extern "C" void kernel_launch(void* const* d_in, const int* in_sizes, int n_in,
                              void* d_out, int out_size, void* d_ws, size_t ws_size,
                              hipStream_t stream) {
    // d_in: 0=t, 1=y, 2=J, 3=anisotropy, 4=gamma, 5=h_dis_x, 6=h_dis_y,
    //       7=beta, 8=e_disorder, 9..14=neighbor index arrays (unused)
    const float* y_    = (const float*)d_in[1];
    const float* Jarr  = (const float*)d_in[2];
    const float* aniso = (const float*)d_in[3];
    const float* gam   = (const float*)d_in[4];
    const float* hdx   = (const float*)d_in[5];
    const float* hdy   = (const float*)d_in[6];
    const float* beta  = (const float*)d_in[7];
    const float* edis  = (const float*)d_in[8];
    float* out = (float*)d_out;

    dgpe_kernel<<<NBLK, 256, 0, stream>>>(y_, Jarr, aniso, gam, hdx, hdy,
                                          beta, edis, out);
}

// Round 8
// 352.953 us; speedup vs baseline: 1.1047x; 1.1047x over previous
//
#include <hip/hip_runtime.h>

// 6-point periodic stencil + DGPE ODE RHS on a 192^3 lattice.
// v7: v1 body (scalar, 1 elem/thread, max TLP — best measured 93.5 µs)
//     with the 21 loads issued as inline-asm global_load_dword, one
//     s_waitcnt vmcnt(0), then compute. v2-v4 post-mortem: the compiler
//     defeated every source-level attempt to keep >6 loads outstanding
//     (VGPR_Count 32/40/20 prove batching + vmcnt(0) drains remained).
//     Volatile asm cannot be split or sunk -> every wave genuinely holds
//     21 loads in flight. sched_barrier(0) after the waitcnt (rule 18)
//     stops VALU consumers hoisting above it.
//     Discriminator: faster => per-wave batching was the wall;
//     flat => MLP exonerated, v1 is the structural plateau.
// Neighbor index arrays unused (arithmetic indices).

#define LDIM 192
#define LSQ  (LDIM * LDIM)          // 36864
#define NTOT (LDIM * LDIM * LDIM)   // 7077888 = 256 * 27648

#define GLOAD(dst, ptr) \
    asm volatile("global_load_dword %0, %1, off" : "=v"(dst) : "v"(ptr))

__global__ __launch_bounds__(256) void dgpe_kernel(
    const float* __restrict__ y,
    const float* __restrict__ Jarr,
    const float* __restrict__ aniso,
    const float* __restrict__ gam,
    const float* __restrict__ hdx,
    const float* __restrict__ hdy,
    const float* __restrict__ beta,
    const float* __restrict__ edis,
    float* __restrict__ out)
{
    const int i = blockIdx.x * blockDim.x + threadIdx.x;

    const float* __restrict__ x = y;
    const float* __restrict__ p = y + NTOT;

    // decompose i = a*L^2 + b*L + c (compiler emits magic-multiply for /192)
    const unsigned ui  = (unsigned)i;
    const unsigned a   = ui / LSQ;
    const unsigned rem = ui - a * LSQ;
    const unsigned b   = rem / LDIM;
    const unsigned c   = rem - b * LDIM;

    // periodic neighbors (flat offsets with wrap)
    const int xm = (a == 0)        ? i + (LDIM - 1) * LSQ  : i - LSQ;
    const int xp = (a == LDIM - 1) ? i - (LDIM - 1) * LSQ  : i + LSQ;
    const int ym = (b == 0)        ? i + (LDIM - 1) * LDIM : i - LDIM;
    const int yp = (b == LDIM - 1) ? i - (LDIM - 1) * LDIM : i + LDIM;
    const int zm = (c == 0)        ? i + (LDIM - 1)        : i - 1;
    const int zp = (c == LDIM - 1) ? i - (LDIM - 1)        : i + 1;

    // ---- 21 loads, all in flight before one waitcnt; fields first ----
    float xi, xxm, xxp, xym, xyp, xzm, xzp;
    float pi, pxm, pxp, pym, pyp, pzm, pzp;
    float Ji, an, g, ed, bt, hx, hy;

    GLOAD(xi,  x + i);
    GLOAD(xxm, x + xm);
    GLOAD(xxp, x + xp);
    GLOAD(xym, x + ym);
    GLOAD(xyp, x + yp);
    GLOAD(xzm, x + zm);
    GLOAD(xzp, x + zp);

    GLOAD(pi,  p + i);
    GLOAD(pxm, p + xm);
    GLOAD(pxp, p + xp);
    GLOAD(pym, p + ym);
    GLOAD(pyp, p + yp);
    GLOAD(pzm, p + zm);
    GLOAD(pzp, p + zp);

    GLOAD(Ji,  Jarr  + i);
    GLOAD(an,  aniso + i);
    GLOAD(g,   gam   + i);
    GLOAD(ed,  edis  + i);
    GLOAD(bt,  beta  + i);
    GLOAD(hx,  hdx   + i);
    GLOAD(hy,  hdy   + i);

    asm volatile("s_waitcnt vmcnt(0)" ::: "memory");
    __builtin_amdgcn_sched_barrier(0);   // rule 18: no consumer hoists above

    const float xL = Ji * (xxm + xxp + xym + xyp + an * (xzm + xzp));
    const float yL = Ji * (pxm + pxp + pym + pyp + an * (pzm + pzp));

    const float r2    = xi * xi + pi * pi;
    const float cross = xL * pi - yL * xi;

    const float dx =  g * pi * cross + ed * pi - yL + hy + bt * r2 * pi;
    const float dp = -g * xi * cross - ed * xi + xL - hx - bt * r2 * xi;

    out[i]        = dx;
    out[i + NTOT] = dp;
}

extern "C" void kernel_launch(void* const* d_in, const int* in_sizes, int n_in,
                              void* d_out, int out_size, void* d_ws, size_t ws_size,
                              hipStream_t stream) {
    // d_in: 0=t, 1=y, 2=J, 3=anisotropy, 4=gamma, 5=h_dis_x, 6=h_dis_y,
    //       7=beta, 8=e_disorder, 9..14=neighbor index arrays (unused)
    const float* y_    = (const float*)d_in[1];
    const float* Jarr  = (const float*)d_in[2];
    const float* aniso = (const float*)d_in[3];
    const float* gam   = (const float*)d_in[4];
    const float* hdx   = (const float*)d_in[5];
    const float* hdy   = (const float*)d_in[6];
    const float* beta  = (const float*)d_in[7];
    const float* edis  = (const float*)d_in[8];
    float* out = (float*)d_out;

    const int threads = 256;
    const int blocks  = NTOT / threads;  // 27648, exact
    dgpe_kernel<<<blocks, threads, 0, stream>>>(y_, Jarr, aniso, gam, hdx, hdy,
                                                beta, edis, out);
}